// Round 6
// baseline (320.407 us; speedup 1.0000x reference)
//
#include <hip/hip_runtime.h>

#define NUM_CODES 1296
#define DDIM 64
#define NUM_Q 131072      // 32*64*64
#define BM 256            // queries per block; 131072 = 512 * 256 exactly
#define BN 192            // codes per N-tile; 7 tiles cover 1296 (last masked)
#define TM 16             // queries per thread
#define TN 12             // codes per thread
#define KC 16             // k-chunk staged in LDS for embeddings
#define SXLD 256          // sx pitch
#define SELD 196          // se pitch (192 + 4)
#define NTILE 7
#define THREADS 256       // 16 ty * 16 tx

// Embedding norms ||e||^2, numpy pairwise (8-accumulator) order, contraction off.
__global__ void vq_enorm(const float* __restrict__ emb, float* __restrict__ norms) {
    int k = blockIdx.x * blockDim.x + threadIdx.x;
    if (k >= NUM_CODES) return;
    const float* e = emb + (size_t)k * DDIM;
    {
#pragma clang fp contract(off)
        float r[8];
#pragma unroll
        for (int j = 0; j < 8; ++j) { float t = e[j] * e[j]; r[j] = t; }
#pragma unroll
        for (int i = 1; i < 8; ++i) {
#pragma unroll
            for (int j = 0; j < 8; ++j) { float t = e[i*8+j] * e[i*8+j]; r[j] += t; }
        }
        norms[k] = ((r[0]+r[1])+(r[2]+r[3])) + ((r[4]+r[5])+(r[6]+r[7]));
    }
}

__global__ __launch_bounds__(THREADS, 2) void vq_main(
        const float* __restrict__ x, const float* __restrict__ emb,
        const float* __restrict__ norms, float* __restrict__ out) {
    __shared__ float sx[DDIM * SXLD];   // 65536 B, x tile k-major
    __shared__ float se[KC * SELD];     // 12544 B, e chunk k-major
    __shared__ float sn[BN];            // 768 B
    __shared__ float x1s[BM];           // 1024 B  -> total 79872 B, 2 blocks/CU

    const int tid = threadIdx.x;
    const int tx = tid & 15;            // code group
    const int ty = tid >> 4;            // query group (0..15)
    const long qbase = (long)blockIdx.x * BM;

    // ---- stage x tile transposed: sx[d][r] = x[qbase+r][d] ----
    // 4096 float4 / 256 threads = 16 each, coalesced global reads.
#pragma unroll
    for (int u = 0; u < 16; ++u) {
        int idx = u * THREADS + tid;
        int r = idx >> 4, j = idx & 15;
        float4 v = *(const float4*)(x + (qbase + r) * DDIM + j * 4);
        sx[(4*j+0)*SXLD + r] = v.x;
        sx[(4*j+1)*SXLD + r] = v.y;
        sx[(4*j+2)*SXLD + r] = v.z;
        sx[(4*j+3)*SXLD + r] = v.w;
    }
    __syncthreads();

    // ---- ||x||^2 per query, numpy pairwise order (element order d=0..63) ----
    {
#pragma clang fp contract(off)
        float r8[8];
#pragma unroll
        for (int j = 0; j < 8; ++j) { float v = sx[j*SXLD + tid]; float t = v*v; r8[j] = t; }
#pragma unroll
        for (int i = 1; i < 8; ++i) {
#pragma unroll
            for (int j = 0; j < 8; ++j) { float v = sx[(i*8+j)*SXLD + tid]; float t = v*v; r8[j] += t; }
        }
        x1s[tid] = ((r8[0]+r8[1])+(r8[2]+r8[3])) + ((r8[4]+r8[5])+(r8[6]+r8[7]));
    }
    // x1s written once; first read is after the next __syncthreads().

    float best[TM]; int bestk[TM];
#pragma unroll
    for (int i = 0; i < TM; ++i) { best[i] = __builtin_inff(); bestk[i] = 0; }

    for (int t = 0; t < NTILE; ++t) {
        const int tb = t * BN;
        float acc[TM][TN];
#pragma unroll
        for (int i = 0; i < TM; ++i)
#pragma unroll
            for (int j = 0; j < TN; ++j) acc[i][j] = 0.f;

        for (int kc = 0; kc < DDIM / KC; ++kc) {
            __syncthreads();   // previous chunk fully consumed
            // stage se[k][c] = emb[clamp(tb+c)][kc*KC + k]; 768 float4 / 256 thr
#pragma unroll
            for (int u = 0; u < 3; ++u) {
                int idx = u * THREADS + tid;
                int c = idx >> 2, j = idx & 3;
                int cg = tb + c; if (cg > NUM_CODES - 1) cg = NUM_CODES - 1;
                float4 v = *(const float4*)(emb + (long)cg * DDIM + kc * KC + j * 4);
                se[(4*j+0)*SELD + c] = v.x;
                se[(4*j+1)*SELD + c] = v.y;
                se[(4*j+2)*SELD + c] = v.z;
                se[(4*j+3)*SELD + c] = v.w;
            }
            if (kc == 0) {
                for (int c = tid; c < BN; c += THREADS)
                    sn[c] = (tb + c < NUM_CODES) ? norms[tb + c] : __builtin_inff();
            }
            __syncthreads();

            for (int k = 0; k < KC; ++k) {
                const float* ap = sx + (kc*KC + k)*SXLD + ty*TM;
                const float* bp = se + k*SELD + tx*TN;
                float av[TM], bv[TN];
#pragma unroll
                for (int p = 0; p < TM/4; ++p) {
                    float4 v = *(const float4*)(ap + 4*p);
                    av[4*p+0]=v.x; av[4*p+1]=v.y; av[4*p+2]=v.z; av[4*p+3]=v.w;
                }
#pragma unroll
                for (int p = 0; p < TN/4; ++p) {
                    float4 v = *(const float4*)(bp + 4*p);
                    bv[4*p+0]=v.x; bv[4*p+1]=v.y; bv[4*p+2]=v.z; bv[4*p+3]=v.w;
                }
#pragma unroll
                for (int i = 0; i < TM; ++i)
#pragma unroll
                    for (int j = 0; j < TN; ++j)
                        acc[i][j] = fmaf(av[i], bv[j], acc[i][j]);  // k ascending: same order as ref
            }
        }

        // ---- argmin update for this tile (codes ascending within thread) ----
#pragma unroll
        for (int i = 0; i < TM; ++i) {
            float x1 = x1s[ty*TM + i];
#pragma unroll
            for (int j = 0; j < TN; ++j) {
                float dist = (x1 + sn[tx*TN + j]) - 2.0f * acc[i][j];
                int kg = tb + tx*TN + j;
                if (dist < best[i]) { best[i] = dist; bestk[i] = kg; }
            }
        }
    }

    // ---- reduce (dist, idx) lexicographically across the 16 tx lanes ----
#pragma unroll
    for (int i = 0; i < TM; ++i) {
        float b = best[i]; int kk = bestk[i];
#pragma unroll
        for (int m = 1; m < 16; m <<= 1) {
            float ob = __shfl_xor(b, m, 64);
            int  ok = __shfl_xor(kk, m, 64);
            if (ob < b || (ob == b && ok < kk)) { b = ob; kk = ok; }
        }
        long q = qbase + ty*TM + i;
        if (tx == 0) out[q] = (float)kk;   // codes as float values
        // 16 lanes gather the 64-float embedding row cooperatively
        *(float4*)(out + (long)NUM_Q + q*DDIM + tx*4) =
            *(const float4*)(emb + (long)kk*DDIM + tx*4);
    }
}

extern "C" void kernel_launch(void* const* d_in, const int* in_sizes, int n_in,
                              void* d_out, int out_size, void* d_ws, size_t ws_size,
                              hipStream_t stream) {
    const float* x   = (const float*)d_in[0];
    const float* emb = (const float*)d_in[1];
    float* norms = (float*)d_ws;   // 1296 floats of scratch

    hipLaunchKernelGGL(vq_enorm, dim3((NUM_CODES + 255) / 256), dim3(256), 0, stream,
                       emb, norms);
    hipLaunchKernelGGL(vq_main, dim3(NUM_Q / BM), dim3(THREADS), 0, stream,
                       x, emb, norms, (float*)d_out);
}

// Round 7
// 306.870 us; speedup vs baseline: 1.0441x; 1.0441x over previous
//
#include <hip/hip_runtime.h>

#define NUM_CODES 1296
#define DDIM 64
#define NUM_Q 131072      // 32*64*64
#define BM 128            // queries per block; 131072 = 1024 * 128 exactly
#define BN 192            // codes per N-tile; 7 tiles cover 1296 (last masked)
#define TM 16             // queries per thread
#define TN 12             // codes per thread
#define KC 8              // k-chunk staged in LDS for embeddings
#define SXLD 128          // sx pitch (P=128: av reads 2-way, staging writes 4-way — both cheap)
#define SELD 196          // se pitch (192 + 4)
#define NTILE 7
#define THREADS 128       // 8 ty * 16 tx

// Embedding norms ||e||^2, numpy pairwise (8-accumulator) order, contraction off.
__global__ void vq_enorm(const float* __restrict__ emb, float* __restrict__ norms) {
    int k = blockIdx.x * blockDim.x + threadIdx.x;
    if (k >= NUM_CODES) return;
    const float* e = emb + (size_t)k * DDIM;
    {
#pragma clang fp contract(off)
        float r[8];
#pragma unroll
        for (int j = 0; j < 8; ++j) { float t = e[j] * e[j]; r[j] = t; }
#pragma unroll
        for (int i = 1; i < 8; ++i) {
#pragma unroll
            for (int j = 0; j < 8; ++j) { float t = e[i*8+j] * e[i*8+j]; r[j] += t; }
        }
        norms[k] = ((r[0]+r[1])+(r[2]+r[3])) + ((r[4]+r[5])+(r[6]+r[7]));
    }
}

// One block = one (M-block, N-tile) pair. blockIdx.x = M-block, blockIdx.y = tile.
__global__ __launch_bounds__(THREADS, 2) void vq_tile(
        const float* __restrict__ x, const float* __restrict__ emb,
        const float* __restrict__ norms, uint2* __restrict__ part) {
    __shared__ float sx[DDIM * SXLD];   // 32768 B, x tile k-major
    __shared__ float se[KC * SELD];     // 6272 B, e chunk k-major
    __shared__ float sn[BN];            // 768 B
    __shared__ float x1s[BM];           // 512 B  -> total 40320 B, 4 blocks/CU

    const int tid = threadIdx.x;
    const int tx = tid & 15;            // code group (within wave)
    const int ty = tid >> 4;            // query group (0..7)
    const long qbase = (long)blockIdx.x * BM;
    const int t = blockIdx.y;
    const int tb = t * BN;

    // ---- stage x tile transposed: sx[d][r] = x[qbase+r][d] ----
    // mapping chosen so each write instruction's lanes span 16 r and 4 j
    // -> 4-way bank conflicts max (cheap, once per block).
#pragma unroll
    for (int u = 0; u < 16; ++u) {
        int r = (tid & 15) + 16 * (u & 7);        // 0..127
        int j = (tid >> 4) + 8 * (u >> 3);        // 0..15 (float4 k-chunk)
        float4 v = *(const float4*)(x + (qbase + r) * DDIM + j * 4);
        sx[(4*j+0)*SXLD + r] = v.x;
        sx[(4*j+1)*SXLD + r] = v.y;
        sx[(4*j+2)*SXLD + r] = v.z;
        sx[(4*j+3)*SXLD + r] = v.w;
    }
    __syncthreads();

    // ---- ||x||^2 per query, numpy pairwise order (element order d=0..63) ----
    {
#pragma clang fp contract(off)
        float r8[8];
#pragma unroll
        for (int j = 0; j < 8; ++j) { float v = sx[j*SXLD + tid]; float t2 = v*v; r8[j] = t2; }
#pragma unroll
        for (int i = 1; i < 8; ++i) {
#pragma unroll
            for (int j = 0; j < 8; ++j) { float v = sx[(i*8+j)*SXLD + tid]; float t2 = v*v; r8[j] += t2; }
        }
        x1s[tid] = ((r8[0]+r8[1])+(r8[2]+r8[3])) + ((r8[4]+r8[5])+(r8[6]+r8[7]));
    }
    // x1s read only in the epilogue, after later __syncthreads().

    float acc[TM][TN];
#pragma unroll
    for (int i = 0; i < TM; ++i)
#pragma unroll
        for (int j = 0; j < TN; ++j) acc[i][j] = 0.f;

    for (int kc = 0; kc < DDIM / KC; ++kc) {
        __syncthreads();   // previous chunk fully consumed
        // stage se[k][c] = emb[clamp(tb+c)][kc*KC + k]; 384 float4 / 128 thr
#pragma unroll
        for (int u = 0; u < 3; ++u) {
            int idx = u * THREADS + tid;
            int c = idx >> 1, j = idx & 1;
            int cg = tb + c; if (cg > NUM_CODES - 1) cg = NUM_CODES - 1;
            float4 v = *(const float4*)(emb + (long)cg * DDIM + kc * KC + j * 4);
            se[(4*j+0)*SELD + c] = v.x;
            se[(4*j+1)*SELD + c] = v.y;
            se[(4*j+2)*SELD + c] = v.z;
            se[(4*j+3)*SELD + c] = v.w;
        }
        if (kc == 0) {
            for (int c = tid; c < BN; c += THREADS)
                sn[c] = (tb + c < NUM_CODES) ? norms[tb + c] : __builtin_inff();
        }
        __syncthreads();

        for (int k = 0; k < KC; ++k) {
            const float* ap = sx + (kc*KC + k)*SXLD + ty*TM;
            const float* bp = se + k*SELD + tx*TN;
            float av[TM], bv[TN];
#pragma unroll
            for (int p = 0; p < TM/4; ++p) {
                float4 v = *(const float4*)(ap + 4*p);
                av[4*p+0]=v.x; av[4*p+1]=v.y; av[4*p+2]=v.z; av[4*p+3]=v.w;
            }
#pragma unroll
            for (int p = 0; p < TN/4; ++p) {
                float4 v = *(const float4*)(bp + 4*p);
                bv[4*p+0]=v.x; bv[4*p+1]=v.y; bv[4*p+2]=v.z; bv[4*p+3]=v.w;
            }
#pragma unroll
            for (int i = 0; i < TM; ++i)
#pragma unroll
                for (int j = 0; j < TN; ++j)
                    acc[i][j] = fmaf(av[i], bv[j], acc[i][j]);  // k ascending: same order as ref
        }
    }

    // ---- per-tile argmin + partial write (best/bestk transient, per i) ----
#pragma unroll
    for (int i = 0; i < TM; ++i) {
        float x1 = x1s[ty*TM + i];
        float b = __builtin_inff(); int bk = 0;
#pragma unroll
        for (int j = 0; j < TN; ++j) {
            float dist = (x1 + sn[tx*TN + j]) - 2.0f * acc[i][j];
            int kg = tb + tx*TN + j;
            if (dist < b) { b = dist; bk = kg; }   // strict < == lowest-index tiebreak
        }
        // reduce (dist, idx) lexicographically across the 16 tx lanes
#pragma unroll
        for (int m = 1; m < 16; m <<= 1) {
            float ob = __shfl_xor(b, m, 64);
            int  ok = __shfl_xor(bk, m, 64);
            if (ob < b || (ob == b && ok < bk)) { b = ob; bk = ok; }
        }
        if (tx == 0) {
            long q = qbase + ty*TM + i;
            part[(long)t * NUM_Q + q] = make_uint2(__float_as_uint(b), (unsigned)bk);
        }
    }
}

// Scan the 7 per-tile partials per query (ascending tile order, strict < ==
// same tie-break as a single ascending-k scan), write codes, gather vectors.
__global__ __launch_bounds__(256) void vq_reduce(
        const uint2* __restrict__ part, const float* __restrict__ emb,
        float* __restrict__ out) {
    __shared__ int skk[256];
    const int tid = threadIdx.x;
    const long qb = (long)blockIdx.x * 256;
    const long q = qb + tid;

    uint2 p0 = part[q];
    float b = __uint_as_float(p0.x); int bk = (int)p0.y;
#pragma unroll
    for (int t = 1; t < NTILE; ++t) {
        uint2 pt = part[(long)t * NUM_Q + q];
        float d = __uint_as_float(pt.x);
        int  k = (int)pt.y;
        if (d < b) { b = d; bk = k; }   // ties keep earlier tile = lower k
    }
    out[q] = (float)bk;                 // codes as float values
    skk[tid] = bk;
    __syncthreads();

    const int tx = tid & 15, ty = tid >> 4;
#pragma unroll
    for (int it = 0; it < 16; ++it) {
        int k2 = skk[ty*16 + it];       // LDS broadcast across the 16-lane group
        long q2 = qb + ty*16 + it;
        *(float4*)(out + (long)NUM_Q + q2*DDIM + tx*4) =
            *(const float4*)(emb + (long)k2*DDIM + tx*4);
    }
}

extern "C" void kernel_launch(void* const* d_in, const int* in_sizes, int n_in,
                              void* d_out, int out_size, void* d_ws, size_t ws_size,
                              hipStream_t stream) {
    const float* x   = (const float*)d_in[0];
    const float* emb = (const float*)d_in[1];
    float* norms = (float*)d_ws;                         // 5184 B
    uint2* part  = (uint2*)((char*)d_ws + 8192);         // 7 * 131072 * 8 B = 7.34 MB

    hipLaunchKernelGGL(vq_enorm, dim3((NUM_CODES + 255) / 256), dim3(256), 0, stream,
                       emb, norms);
    hipLaunchKernelGGL(vq_tile, dim3(NUM_Q / BM, NTILE), dim3(THREADS), 0, stream,
                       x, emb, norms, part);
    hipLaunchKernelGGL(vq_reduce, dim3(NUM_Q / 256), dim3(256), 0, stream,
                       part, emb, (float*)d_out);
}